// Round 1
// baseline (706.494 us; speedup 1.0000x reference)
//
#include <hip/hip_runtime.h>
#include <math.h>

#define EPSV 1e-12f

// ---- sizes ----
// O=I=2048, H=W=3, M=9, IHW=18432 floats per o-slab
// tile: 64 o x 64 i per block; 1024 blocks; 256 threads
// thread: u = t&15 (i-group, 4 consecutive i), a = t>>4 ; o = o0 + a + 16k, k=0..3
//
// K permuted copy (Kp, stored in d_out which is dead until scaleK):
// within each (o, bi) tile of 144 float4, Kp[tile*144 + 16*c + u] = K[tile*144 + 9*u + c]
// -> pass loads Kp4[p4base + 16*c], lanes u=0..15 consecutive float4 = coalesced.

// ---- workspace layout (floats) ----
#define WS_U1 0          // 6144  u1[i*3+w]
#define WS_U2 6144       // 6144  u2[i*3+h]
#define WS_U3 12288      // 18432 u3[i*9+m]
#define WS_U4 30720      // 18432 u4[o*9+m]
#define WS_V1 49152      // 6144  v1[o*3+h]
#define WS_V2 55296      // 6144  v2[o*3+w]
#define WS_V3 61440      // 2048  v3[o]
#define WS_V4 63488      // 2048  v4[i]
#define WS_NU 65536      // 4
#define WS_NV 65540      // 4
#define WS_SIG 65544     // 1  (inv sigma)

__device__ __forceinline__ void gAtomicAdd(float* p, float v) {
    unsafeAtomicAdd(p, v);   // global_atomic_add_f32 on gfx950
}

__device__ __forceinline__ float wsum16(float v) {   // sum over 16 consecutive lanes
    v += __shfl_xor(v, 1);  v += __shfl_xor(v, 2);
    v += __shfl_xor(v, 4);  v += __shfl_xor(v, 8);
    return v;
}
__device__ __forceinline__ float wsum4x16(float v) { // sum over lanes {u,u+16,u+32,u+48}
    v += __shfl_xor(v, 16); v += __shfl_xor(v, 32);
    return v;
}

__device__ __forceinline__ float blockReduceSum(float v) {
    __shared__ float sh[4];
    #pragma unroll
    for (int off = 1; off < 64; off <<= 1) v += __shfl_xor(v, off);
    const int w = threadIdx.x >> 6;
    if ((threadIdx.x & 63) == 0) sh[w] = v;
    __syncthreads();
    float r = 0.f;
    if (threadIdx.x == 0) r = sh[0] + sh[1] + sh[2] + sh[3];
    return r;
}

// zero v-raws + nu + nv (contiguous range [WS_V1, WS_SIG))
__global__ void initZero(float* ws) {
    for (int i = threadIdx.x; i < 16392; i += 256) ws[WS_V1 + i] = 0.f;
}

// copy input u's into ws, accumulate squared norms into nu[4]
__global__ void initU(const float* __restrict__ u1, const float* __restrict__ u2,
                      const float* __restrict__ u3, const float* __restrict__ u4,
                      float* __restrict__ ws) {
    const int tid = blockIdx.x * 256 + threadIdx.x;   // grid 192*256 = 49152
    float val; int c;
    if (tid < 6144)       { val = u1[tid];          c = 0; }
    else if (tid < 12288) { val = u2[tid - 6144];   c = 1; }
    else if (tid < 30720) { val = u3[tid - 12288];  c = 2; }
    else                  { val = u4[tid - 30720];  c = 3; }
    ws[WS_U1 + tid] = val;
    float bs = blockReduceSum(val * val);
    if (threadIdx.x == 0) gAtomicAdd(&ws[WS_NU + c], bs);
}

// permute K into coalesced-pass layout (writes coalesced; reads within 2304B windows)
__global__ __launch_bounds__(256) void permuteK(const float4* __restrict__ K4,
                                                float4* __restrict__ Kp4) {
    const int idx = blockIdx.x * 256 + threadIdx.x;   // grid 4608*256
    #pragma unroll
    for (int r = 0; r < 8; ++r) {
        const int j = idx + r * 1179648;              // output float4 index
        const int tile = j / 144;                     // magic-mul div by const
        const int rr = j - tile * 144;
        const int c = rr >> 4, u = rr & 15;
        Kp4[j] = K4[tile * 144 + 9 * u + c];
    }
}

#define PROC_V(off, kvv) { \
    const int iq = (off) / 9, mm = (off) % 9, hh = mm / 3, wq = mm % 3; \
    b1[hh]  += (kvv) * w1[iq * 3 + wq]; \
    b2[wq]  += (kvv) * w2[iq * 3 + hh]; \
    b3      += (kvv) * u3v[off]; \
    a4[iq]  += (kvv) * u4row[mm]; }

__global__ __launch_bounds__(256) void passV(const float4* __restrict__ Kp4,
                                             float* __restrict__ ws) {
    const int b  = blockIdx.x;
    const int bo = b >> 5, bi = b & 31;
    const int o0 = bo * 64, i0 = bi * 64;
    const int t = threadIdx.x;
    const int u = t & 15, a = t >> 4;
    const int lane = t & 63;

    const float inv1 = 1.f / (sqrtf(ws[WS_NU + 0]) + EPSV);
    const float inv2 = 1.f / (sqrtf(ws[WS_NU + 1]) + EPSV);
    const float inv3 = 1.f / (sqrtf(ws[WS_NU + 2]) + EPSV);
    const float inv4 = 1.f / (sqrtf(ws[WS_NU + 3]) + EPSV);

    const int ib = i0 + 4 * u;          // first i of this thread
    // thread-fixed i-side weights
    float w1[12], w2[12], u3v[36];
    {
        const float4* U1v = reinterpret_cast<const float4*>(ws + WS_U1);
        const float4* U2v = reinterpret_cast<const float4*>(ws + WS_U2);
        const float4* U3v = reinterpret_cast<const float4*>(ws + WS_U3);
        #pragma unroll
        for (int q = 0; q < 3; ++q) {
            float4 f = U1v[(ib * 3) / 4 + q];
            w1[4 * q + 0] = f.x * inv1; w1[4 * q + 1] = f.y * inv1;
            w1[4 * q + 2] = f.z * inv1; w1[4 * q + 3] = f.w * inv1;
            float4 g = U2v[(ib * 3) / 4 + q];
            w2[4 * q + 0] = g.x * inv2; w2[4 * q + 1] = g.y * inv2;
            w2[4 * q + 2] = g.z * inv2; w2[4 * q + 3] = g.w * inv2;
        }
        #pragma unroll
        for (int q = 0; q < 9; ++q) {
            float4 f = U3v[(ib * 9) / 4 + q];
            u3v[4 * q + 0] = f.x * inv3; u3v[4 * q + 1] = f.y * inv3;
            u3v[4 * q + 2] = f.z * inv3; u3v[4 * q + 3] = f.w * inv3;
        }
    }

    float a4[4] = {0.f, 0.f, 0.f, 0.f};
    for (int k = 0; k < 4; ++k) {
        const int o = o0 + a + 16 * k;
        float u4row[9];
        #pragma unroll
        for (int m = 0; m < 9; ++m) u4row[m] = ws[WS_U4 + o * 9 + m] * inv4;
        const int p4base = o * 4608 + bi * 144 + u;   // coalesced: +16*c per load
        float b1[3] = {0.f, 0.f, 0.f}, b2[3] = {0.f, 0.f, 0.f}, b3 = 0.f;
        #pragma unroll
        for (int c = 0; c < 9; ++c) {
            float4 kq = Kp4[p4base + 16 * c];
            { const int off = 4 * c + 0; PROC_V(off, kq.x); }
            { const int off = 4 * c + 1; PROC_V(off, kq.y); }
            { const int off = 4 * c + 2; PROC_V(off, kq.z); }
            { const int off = 4 * c + 3; PROC_V(off, kq.w); }
        }
        #pragma unroll
        for (int hh = 0; hh < 3; ++hh) {
            float s = wsum16(b1[hh]);
            if (u == 0) gAtomicAdd(&ws[WS_V1 + o * 3 + hh], s);
        }
        #pragma unroll
        for (int wq = 0; wq < 3; ++wq) {
            float s = wsum16(b2[wq]);
            if (u == 0) gAtomicAdd(&ws[WS_V2 + o * 3 + wq], s);
        }
        {
            float s = wsum16(b3);
            if (u == 0) gAtomicAdd(&ws[WS_V3 + o], s);
        }
    }
    #pragma unroll
    for (int iq = 0; iq < 4; ++iq) {
        float s = wsum4x16(a4[iq]);
        if (lane < 16) gAtomicAdd(&ws[WS_V4 + i0 + 4 * u + iq], s);
    }
}

// nv += sum v^2 ; zero u-raws and nu
__global__ void normVzeroU(float* __restrict__ ws) {
    const int tid = blockIdx.x * 256 + threadIdx.x;   // grid 192*256
    float val = 0.f; int c = 3;
    if (tid < 16384) {
        val = ws[WS_V1 + tid];
        c = (tid < 6144) ? 0 : (tid < 12288) ? 1 : (tid < 14336) ? 2 : 3;
    }
    float bs = blockReduceSum(val * val);
    if (threadIdx.x == 0 && blockIdx.x < 64) gAtomicAdd(&ws[WS_NV + c], bs);
    ws[WS_U1 + tid] = 0.f;                 // tid < 49152 always
    if (tid < 4) ws[WS_NU + tid] = 0.f;
}

#define PROC_U(off, kvv) { \
    const int iq = (off) / 9, mm = (off) % 9, hh = mm / 3, wq = mm % 3; \
    c1[iq * 3 + wq] += (kvv) * v1row[hh]; \
    c2[iq * 3 + hh] += (kvv) * v2row[wq]; \
    c3[off]         += (kvv) * v3v; \
    d4[mm]          += (kvv) * v4val[iq]; }

__global__ __launch_bounds__(256) void passU(const float4* __restrict__ Kp4,
                                             float* __restrict__ ws) {
    __shared__ float red[3840];
    const int b  = blockIdx.x;
    const int bo = b >> 5, bi = b & 31;
    const int o0 = bo * 64, i0 = bi * 64;
    const int t = threadIdx.x;
    const int u = t & 15, a = t >> 4;
    const int lane = t & 63, Wv = t >> 6;

    const float iv1 = 1.f / (sqrtf(ws[WS_NV + 0]) + EPSV);
    const float iv2 = 1.f / (sqrtf(ws[WS_NV + 1]) + EPSV);
    const float iv3 = 1.f / (sqrtf(ws[WS_NV + 2]) + EPSV);
    const float iv4 = 1.f / (sqrtf(ws[WS_NV + 3]) + EPSV);

    const int ib = i0 + 4 * u;
    float v4val[4];
    {
        float4 f = *reinterpret_cast<const float4*>(ws + WS_V4 + ib);
        v4val[0] = f.x * iv4; v4val[1] = f.y * iv4;
        v4val[2] = f.z * iv4; v4val[3] = f.w * iv4;
    }

    float c1[12], c2[12], c3[36];
    #pragma unroll
    for (int v = 0; v < 12; ++v) { c1[v] = 0.f; c2[v] = 0.f; }
    #pragma unroll
    for (int v = 0; v < 36; ++v) c3[v] = 0.f;

    for (int k = 0; k < 4; ++k) {
        const int o = o0 + a + 16 * k;
        float v1row[3], v2row[3];
        #pragma unroll
        for (int hh = 0; hh < 3; ++hh) v1row[hh] = ws[WS_V1 + o * 3 + hh] * iv1;
        #pragma unroll
        for (int wq = 0; wq < 3; ++wq) v2row[wq] = ws[WS_V2 + o * 3 + wq] * iv2;
        const float v3v = ws[WS_V3 + o] * iv3;
        const int p4base = o * 4608 + bi * 144 + u;   // coalesced: +16*c per load
        float d4[9];
        #pragma unroll
        for (int m = 0; m < 9; ++m) d4[m] = 0.f;
        #pragma unroll
        for (int c = 0; c < 9; ++c) {
            float4 kq = Kp4[p4base + 16 * c];
            { const int off = 4 * c + 0; PROC_U(off, kq.x); }
            { const int off = 4 * c + 1; PROC_U(off, kq.y); }
            { const int off = 4 * c + 2; PROC_U(off, kq.z); }
            { const int off = 4 * c + 3; PROC_U(off, kq.w); }
        }
        #pragma unroll
        for (int m = 0; m < 9; ++m) {
            float s = wsum16(d4[m]);
            if (u == 0) gAtomicAdd(&ws[WS_U4 + o * 9 + m], s);
        }
    }

    // chains 1-3: sum over this wave's 4 a-groups, then across 4 waves via LDS
    #pragma unroll
    for (int v = 0; v < 12; ++v) { c1[v] = wsum4x16(c1[v]); c2[v] = wsum4x16(c2[v]); }
    #pragma unroll
    for (int v = 0; v < 36; ++v) c3[v] = wsum4x16(c3[v]);
    if (lane < 16) {
        float* dst = &red[Wv * 960 + lane * 60];
        #pragma unroll
        for (int v = 0; v < 12; ++v) dst[v] = c1[v];
        #pragma unroll
        for (int v = 0; v < 12; ++v) dst[12 + v] = c2[v];
        #pragma unroll
        for (int v = 0; v < 36; ++v) dst[24 + v] = c3[v];
    }
    __syncthreads();
    for (int s0 = t; s0 < 960; s0 += 256) {
        float sum = red[s0] + red[960 + s0] + red[1920 + s0] + red[2880 + s0];
        const int uu = s0 / 60, v = s0 % 60;
        const int ibase = i0 + 4 * uu;
        if (v < 12) {
            gAtomicAdd(&ws[WS_U1 + (ibase + v / 3) * 3 + (v % 3)], sum);
        } else if (v < 24) {
            const int vv = v - 12;
            gAtomicAdd(&ws[WS_U2 + (ibase + vv / 3) * 3 + (vv % 3)], sum);
        } else {
            const int vv = v - 24;
            gAtomicAdd(&ws[WS_U3 + ibase * 9 + vv], sum);
        }
    }
}

// nu += sum u^2 ; zero v-raws and nv
__global__ void normUzeroV(float* __restrict__ ws) {
    const int tid = blockIdx.x * 256 + threadIdx.x;   // grid 192*256 = 49152
    float val = ws[WS_U1 + tid];
    int c = (tid < 6144) ? 0 : (tid < 12288) ? 1 : (tid < 30720) ? 2 : 3;
    float bs = blockReduceSum(val * val);
    if (threadIdx.x == 0) gAtomicAdd(&ws[WS_NU + c], bs);
    if (tid < 16384) ws[WS_V1 + tid] = 0.f;
    if (tid < 4) ws[WS_NV + tid] = 0.f;
}

__global__ void sigmaK(float* __restrict__ ws) {
    if (threadIdx.x == 0) {
        float smin = 1e30f;
        #pragma unroll
        for (int c = 0; c < 4; ++c) {
            float S = ws[WS_NU + c];
            float sg = S / (sqrtf(S) + EPSV);
            smin = fminf(smin, sg);
        }
        ws[WS_SIG] = 1.0f / smin;
    }
}

__global__ __launch_bounds__(256) void scaleK(const float4* __restrict__ K4,
                                              const float* __restrict__ ws,
                                              float4* __restrict__ out4) {
    const float inv = ws[WS_SIG];
    const int idx = blockIdx.x * 256 + threadIdx.x;   // grid 4608*256
    #pragma unroll
    for (int r = 0; r < 8; ++r) {
        const int j = idx + r * 1179648;
        float4 kq = K4[j];
        kq.x *= inv; kq.y *= inv; kq.z *= inv; kq.w *= inv;
        out4[j] = kq;
    }
}

extern "C" void kernel_launch(void* const* d_in, const int* in_sizes, int n_in,
                              void* d_out, int out_size, void* d_ws, size_t ws_size,
                              hipStream_t stream) {
    const float4* K4 = (const float4*)d_in[0];
    float* ws = (float*)d_ws;                 // needs 262,180 bytes
    float4* out4 = (float4*)d_out;
    const float4* Kp4 = (const float4*)d_out; // permuted K lives in d_out until scaleK

    permuteK<<<4608, 256, 0, stream>>>(K4, (float4*)d_out);
    initZero<<<1, 256, 0, stream>>>(ws);
    initU<<<192, 256, 0, stream>>>((const float*)d_in[1], (const float*)d_in[2],
                                   (const float*)d_in[3], (const float*)d_in[4], ws);
    for (int it = 0; it < 3; ++it) {
        passV<<<1024, 256, 0, stream>>>(Kp4, ws);
        normVzeroU<<<192, 256, 0, stream>>>(ws);
        passU<<<1024, 256, 0, stream>>>(Kp4, ws);
        normUzeroV<<<192, 256, 0, stream>>>(ws);
    }
    sigmaK<<<1, 64, 0, stream>>>(ws);
    scaleK<<<4608, 256, 0, stream>>>(K4, ws, out4);
}

// Round 2
// 668.476 us; speedup vs baseline: 1.0569x; 1.0569x over previous
//
#include <hip/hip_runtime.h>
#include <math.h>

#define EPSV 1e-12f

// ---- sizes ----
// O=I=2048, H=W=3, M=9, IHW=18432 floats per o-slab
// tile: 64 o x 64 i per block; 1024 blocks; 256 threads
// thread: u = t&15 (i-group, 4 consecutive i), a = t>>4 ; o = o0 + a + 16k, k=0..3
// wave wv = t>>6 owns a in {4wv..4wv+3}; la = a&3; lane = t&63 = la*16+u
//
// K staging: wave-private double-buffered LDS via global_load_lds (no barriers).
// One glds chunk c: lane l <- K4[(o0+4wv+(l>>4)+16k)*4608 + bi*144 + 9*(l&15) + c]
// written linearly at st[buf][wv][c][l]. Reader (u,a) gets its old K4[f4base+c]
// at st[buf][wv][c][lane]. Identical arithmetic to the direct-load version.

// ---- workspace layout (floats) ----
#define WS_U1 0          // 6144  u1[i*3+w]
#define WS_U2 6144       // 6144  u2[i*3+h]
#define WS_U3 12288      // 18432 u3[i*9+m]
#define WS_U4 30720      // 18432 u4[o*9+m]
#define WS_V1 49152      // 6144  v1[o*3+h]
#define WS_V2 55296      // 6144  v2[o*3+w]
#define WS_V3 61440      // 2048  v3[o]
#define WS_V4 63488      // 2048  v4[i]
#define WS_NU 65536      // 4
#define WS_NV 65540      // 4
#define WS_SIG 65544     // 1  (inv sigma)

__device__ __forceinline__ void gAtomicAdd(float* p, float v) {
    unsafeAtomicAdd(p, v);   // global_atomic_add_f32 on gfx950
}

__device__ __forceinline__ float wsum16(float v) {   // sum over 16 consecutive lanes
    v += __shfl_xor(v, 1);  v += __shfl_xor(v, 2);
    v += __shfl_xor(v, 4);  v += __shfl_xor(v, 8);
    return v;
}
__device__ __forceinline__ float wsum4x16(float v) { // sum over lanes {u,u+16,u+32,u+48}
    v += __shfl_xor(v, 16); v += __shfl_xor(v, 32);
    return v;
}

__device__ __forceinline__ float blockReduceSum(float v) {
    __shared__ float sh[4];
    #pragma unroll
    for (int off = 1; off < 64; off <<= 1) v += __shfl_xor(v, off);
    const int w = threadIdx.x >> 6;
    if ((threadIdx.x & 63) == 0) sh[w] = v;
    __syncthreads();
    float r = 0.f;
    if (threadIdx.x == 0) r = sh[0] + sh[1] + sh[2] + sh[3];
    return r;
}

// zero v-raws + nu + nv (contiguous range [WS_V1, WS_SIG))
__global__ void initZero(float* ws) {
    for (int i = threadIdx.x; i < 16392; i += 256) ws[WS_V1 + i] = 0.f;
}

// copy input u's into ws, accumulate squared norms into nu[4]
__global__ void initU(const float* __restrict__ u1, const float* __restrict__ u2,
                      const float* __restrict__ u3, const float* __restrict__ u4,
                      float* __restrict__ ws) {
    const int tid = blockIdx.x * 256 + threadIdx.x;   // grid 192*256 = 49152
    float val; int c;
    if (tid < 6144)       { val = u1[tid];          c = 0; }
    else if (tid < 12288) { val = u2[tid - 6144];   c = 1; }
    else if (tid < 30720) { val = u3[tid - 12288];  c = 2; }
    else                  { val = u4[tid - 30720];  c = 3; }
    ws[WS_U1 + tid] = val;
    float bs = blockReduceSum(val * val);
    if (threadIdx.x == 0) gAtomicAdd(&ws[WS_NU + c], bs);
}

// ---- wave-private K staging (double buffer, counted vmcnt, no barriers) ----
#define STAGE(kk, bufc) do {                                                       \
    const float4* s_ = K4 + (size_t)(o0 + a + 16 * (kk)) * 4608 + bi * 144 + 9 * u;\
    _Pragma("unroll")                                                              \
    for (int c_ = 0; c_ < 9; ++c_)                                                 \
        __builtin_amdgcn_global_load_lds(                                          \
            (const __attribute__((address_space(1))) void*)(s_ + c_),              \
            (__attribute__((address_space(3))) void*)&st[bufc][wv][c_][0],         \
            16, 0, 0);                                                             \
} while (0)

#define VMWAIT(N) do {                                                             \
    __builtin_amdgcn_sched_barrier(0);                                             \
    asm volatile("s_waitcnt vmcnt(" #N ")" ::: "memory");                          \
    __builtin_amdgcn_sched_barrier(0);                                             \
} while (0)

#define PROC_V(off, kvv) { \
    const int iq = (off) / 9, mm = (off) % 9, hh = mm / 3, wq = mm % 3; \
    b1[hh]  += (kvv) * w1[iq * 3 + wq]; \
    b2[wq]  += (kvv) * w2[iq * 3 + hh]; \
    b3      += (kvv) * u3v[off]; \
    a4[iq]  += (kvv) * u4row[mm]; }

__global__ __launch_bounds__(256, 2) void passV(const float4* __restrict__ K4,
                                                float* __restrict__ ws) {
    __shared__ float4 st[2][4][9][64];   // 73728 B, wave-private quarters
    const int b  = blockIdx.x;
    const int bo = b >> 5, bi = b & 31;
    const int o0 = bo * 64, i0 = bi * 64;
    const int t = threadIdx.x;
    const int u = t & 15, a = t >> 4;
    const int lane = t & 63, wv = t >> 6;

    STAGE(0, 0);   // prefetch k=0 immediately

    const float inv1 = 1.f / (sqrtf(ws[WS_NU + 0]) + EPSV);
    const float inv2 = 1.f / (sqrtf(ws[WS_NU + 1]) + EPSV);
    const float inv3 = 1.f / (sqrtf(ws[WS_NU + 2]) + EPSV);
    const float inv4 = 1.f / (sqrtf(ws[WS_NU + 3]) + EPSV);

    const int ib = i0 + 4 * u;          // first i of this thread
    // thread-fixed i-side weights
    float w1[12], w2[12], u3v[36];
    {
        const float4* U1v = reinterpret_cast<const float4*>(ws + WS_U1);
        const float4* U2v = reinterpret_cast<const float4*>(ws + WS_U2);
        const float4* U3v = reinterpret_cast<const float4*>(ws + WS_U3);
        #pragma unroll
        for (int q = 0; q < 3; ++q) {
            float4 f = U1v[(ib * 3) / 4 + q];
            w1[4 * q + 0] = f.x * inv1; w1[4 * q + 1] = f.y * inv1;
            w1[4 * q + 2] = f.z * inv1; w1[4 * q + 3] = f.w * inv1;
            float4 g = U2v[(ib * 3) / 4 + q];
            w2[4 * q + 0] = g.x * inv2; w2[4 * q + 1] = g.y * inv2;
            w2[4 * q + 2] = g.z * inv2; w2[4 * q + 3] = g.w * inv2;
        }
        #pragma unroll
        for (int q = 0; q < 9; ++q) {
            float4 f = U3v[(ib * 9) / 4 + q];
            u3v[4 * q + 0] = f.x * inv3; u3v[4 * q + 1] = f.y * inv3;
            u3v[4 * q + 2] = f.z * inv3; u3v[4 * q + 3] = f.w * inv3;
        }
    }

    float a4[4] = {0.f, 0.f, 0.f, 0.f};
    #pragma unroll
    for (int k = 0; k < 4; ++k) {
        const int o = o0 + a + 16 * k;
        float u4row[9];
        #pragma unroll
        for (int m = 0; m < 9; ++m) u4row[m] = ws[WS_U4 + o * 9 + m] * inv4;
        __builtin_amdgcn_sched_barrier(0);
        if (k < 3) { STAGE(k + 1, (k + 1) & 1); VMWAIT(9); }
        else       { VMWAIT(0); }

        float b1[3] = {0.f, 0.f, 0.f}, b2[3] = {0.f, 0.f, 0.f}, b3 = 0.f;
        #pragma unroll
        for (int c = 0; c < 9; ++c) {
            float4 kq = st[k & 1][wv][c][lane];
            { const int off = 4 * c + 0; PROC_V(off, kq.x); }
            { const int off = 4 * c + 1; PROC_V(off, kq.y); }
            { const int off = 4 * c + 2; PROC_V(off, kq.z); }
            { const int off = 4 * c + 3; PROC_V(off, kq.w); }
        }
        #pragma unroll
        for (int hh = 0; hh < 3; ++hh) {
            float s = wsum16(b1[hh]);
            if (u == 0) gAtomicAdd(&ws[WS_V1 + o * 3 + hh], s);
        }
        #pragma unroll
        for (int wq = 0; wq < 3; ++wq) {
            float s = wsum16(b2[wq]);
            if (u == 0) gAtomicAdd(&ws[WS_V2 + o * 3 + wq], s);
        }
        {
            float s = wsum16(b3);
            if (u == 0) gAtomicAdd(&ws[WS_V3 + o], s);
        }
    }
    #pragma unroll
    for (int iq = 0; iq < 4; ++iq) {
        float s = wsum4x16(a4[iq]);
        if (lane < 16) gAtomicAdd(&ws[WS_V4 + i0 + 4 * u + iq], s);
    }
}

// nv += sum v^2 ; zero u-raws and nu
__global__ void normVzeroU(float* __restrict__ ws) {
    const int tid = blockIdx.x * 256 + threadIdx.x;   // grid 192*256
    float val = 0.f; int c = 3;
    if (tid < 16384) {
        val = ws[WS_V1 + tid];
        c = (tid < 6144) ? 0 : (tid < 12288) ? 1 : (tid < 14336) ? 2 : 3;
    }
    float bs = blockReduceSum(val * val);
    if (threadIdx.x == 0 && blockIdx.x < 64) gAtomicAdd(&ws[WS_NV + c], bs);
    ws[WS_U1 + tid] = 0.f;                 // tid < 49152 always
    if (tid < 4) ws[WS_NU + tid] = 0.f;
}

#define PROC_U(off, kvv) { \
    const int iq = (off) / 9, mm = (off) % 9, hh = mm / 3, wq = mm % 3; \
    c1[iq * 3 + wq] += (kvv) * v1row[hh]; \
    c2[iq * 3 + hh] += (kvv) * v2row[wq]; \
    c3[off]         += (kvv) * v3v; \
    d4[mm]          += (kvv) * v4val[iq]; }

__global__ __launch_bounds__(256, 2) void passU(const float4* __restrict__ K4,
                                                float* __restrict__ ws) {
    __shared__ float4 st[2][4][9][64];   // 73728 B; tail-reduce scratch aliases this
    float* red = reinterpret_cast<float*>(st);
    const int b  = blockIdx.x;
    const int bo = b >> 5, bi = b & 31;
    const int o0 = bo * 64, i0 = bi * 64;
    const int t = threadIdx.x;
    const int u = t & 15, a = t >> 4;
    const int lane = t & 63, wv = t >> 6;

    STAGE(0, 0);   // prefetch k=0 immediately

    const float iv1 = 1.f / (sqrtf(ws[WS_NV + 0]) + EPSV);
    const float iv2 = 1.f / (sqrtf(ws[WS_NV + 1]) + EPSV);
    const float iv3 = 1.f / (sqrtf(ws[WS_NV + 2]) + EPSV);
    const float iv4 = 1.f / (sqrtf(ws[WS_NV + 3]) + EPSV);

    const int ib = i0 + 4 * u;
    float v4val[4];
    {
        float4 f = *reinterpret_cast<const float4*>(ws + WS_V4 + ib);
        v4val[0] = f.x * iv4; v4val[1] = f.y * iv4;
        v4val[2] = f.z * iv4; v4val[3] = f.w * iv4;
    }

    float c1[12], c2[12], c3[36];
    #pragma unroll
    for (int v = 0; v < 12; ++v) { c1[v] = 0.f; c2[v] = 0.f; }
    #pragma unroll
    for (int v = 0; v < 36; ++v) c3[v] = 0.f;

    #pragma unroll
    for (int k = 0; k < 4; ++k) {
        const int o = o0 + a + 16 * k;
        float v1row[3], v2row[3];
        #pragma unroll
        for (int hh = 0; hh < 3; ++hh) v1row[hh] = ws[WS_V1 + o * 3 + hh] * iv1;
        #pragma unroll
        for (int wq = 0; wq < 3; ++wq) v2row[wq] = ws[WS_V2 + o * 3 + wq] * iv2;
        const float v3v = ws[WS_V3 + o] * iv3;
        __builtin_amdgcn_sched_barrier(0);
        if (k < 3) { STAGE(k + 1, (k + 1) & 1); VMWAIT(9); }
        else       { VMWAIT(0); }

        float d4[9];
        #pragma unroll
        for (int m = 0; m < 9; ++m) d4[m] = 0.f;
        #pragma unroll
        for (int c = 0; c < 9; ++c) {
            float4 kq = st[k & 1][wv][c][lane];
            { const int off = 4 * c + 0; PROC_U(off, kq.x); }
            { const int off = 4 * c + 1; PROC_U(off, kq.y); }
            { const int off = 4 * c + 2; PROC_U(off, kq.z); }
            { const int off = 4 * c + 3; PROC_U(off, kq.w); }
        }
        #pragma unroll
        for (int m = 0; m < 9; ++m) {
            float s = wsum16(d4[m]);
            if (u == 0) gAtomicAdd(&ws[WS_U4 + o * 9 + m], s);
        }
    }

    // chains 1-3: sum over this wave's 4 a-groups, then across 4 waves via LDS
    #pragma unroll
    for (int v = 0; v < 12; ++v) { c1[v] = wsum4x16(c1[v]); c2[v] = wsum4x16(c2[v]); }
    #pragma unroll
    for (int v = 0; v < 36; ++v) c3[v] = wsum4x16(c3[v]);
    __syncthreads();   // red aliases staging LDS: all waves must be done consuming
    if (lane < 16) {
        float* dst = &red[wv * 960 + lane * 60];
        #pragma unroll
        for (int v = 0; v < 12; ++v) dst[v] = c1[v];
        #pragma unroll
        for (int v = 0; v < 12; ++v) dst[12 + v] = c2[v];
        #pragma unroll
        for (int v = 0; v < 36; ++v) dst[24 + v] = c3[v];
    }
    __syncthreads();
    for (int s0 = t; s0 < 960; s0 += 256) {
        float sum = red[s0] + red[960 + s0] + red[1920 + s0] + red[2880 + s0];
        const int uu = s0 / 60, v = s0 % 60;
        const int ibase = i0 + 4 * uu;
        if (v < 12) {
            gAtomicAdd(&ws[WS_U1 + (ibase + v / 3) * 3 + (v % 3)], sum);
        } else if (v < 24) {
            const int vv = v - 12;
            gAtomicAdd(&ws[WS_U2 + (ibase + vv / 3) * 3 + (vv % 3)], sum);
        } else {
            const int vv = v - 24;
            gAtomicAdd(&ws[WS_U3 + ibase * 9 + vv], sum);
        }
    }
}

// nu += sum u^2 ; zero v-raws and nv
__global__ void normUzeroV(float* __restrict__ ws) {
    const int tid = blockIdx.x * 256 + threadIdx.x;   // grid 192*256 = 49152
    float val = ws[WS_U1 + tid];
    int c = (tid < 6144) ? 0 : (tid < 12288) ? 1 : (tid < 30720) ? 2 : 3;
    float bs = blockReduceSum(val * val);
    if (threadIdx.x == 0) gAtomicAdd(&ws[WS_NU + c], bs);
    if (tid < 16384) ws[WS_V1 + tid] = 0.f;
    if (tid < 4) ws[WS_NV + tid] = 0.f;
}

__global__ void sigmaK(float* __restrict__ ws) {
    if (threadIdx.x == 0) {
        float smin = 1e30f;
        #pragma unroll
        for (int c = 0; c < 4; ++c) {
            float S = ws[WS_NU + c];
            float sg = S / (sqrtf(S) + EPSV);
            smin = fminf(smin, sg);
        }
        ws[WS_SIG] = 1.0f / smin;
    }
}

__global__ __launch_bounds__(256) void scaleK(const float4* __restrict__ K4,
                                              const float* __restrict__ ws,
                                              float4* __restrict__ out4) {
    const float inv = ws[WS_SIG];
    const int idx = blockIdx.x * 256 + threadIdx.x;   // grid 4608*256
    #pragma unroll
    for (int r = 0; r < 8; ++r) {
        const int j = idx + r * 1179648;
        float4 kq = K4[j];
        kq.x *= inv; kq.y *= inv; kq.z *= inv; kq.w *= inv;
        out4[j] = kq;
    }
}

extern "C" void kernel_launch(void* const* d_in, const int* in_sizes, int n_in,
                              void* d_out, int out_size, void* d_ws, size_t ws_size,
                              hipStream_t stream) {
    const float4* K4 = (const float4*)d_in[0];
    float* ws = (float*)d_ws;                 // needs 262,180 bytes
    float4* out4 = (float4*)d_out;

    initZero<<<1, 256, 0, stream>>>(ws);
    initU<<<192, 256, 0, stream>>>((const float*)d_in[1], (const float*)d_in[2],
                                   (const float*)d_in[3], (const float*)d_in[4], ws);
    for (int it = 0; it < 3; ++it) {
        passV<<<1024, 256, 0, stream>>>(K4, ws);
        normVzeroU<<<192, 256, 0, stream>>>(ws);
        passU<<<1024, 256, 0, stream>>>(K4, ws);
        normUzeroV<<<192, 256, 0, stream>>>(ws);
    }
    sigmaK<<<1, 64, 0, stream>>>(ws);
    scaleK<<<4608, 256, 0, stream>>>(K4, ws, out4);
}

// Round 3
// 500.360 us; speedup vs baseline: 1.4120x; 1.3360x over previous
//
#include <hip/hip_runtime.h>
#include <math.h>

#define EPSV 1e-12f

// ---- sizes ----
// O=I=2048, H=W=3, M=9, IHW=18432 floats per o-slab
// tile: 64 o x 64 i per block; 1024 blocks; 256 threads
// thread: u = t&15 (i-group, 4 consecutive i), a = t>>4 ; o = o0 + a + 16k, k=0..3
//
// NO global atomics in the hot passes: per-block partials go to scratch in d_out
// (dead until scaleK), plain coalesced stores; the norm kernels reduce them.
//
// scratch layout in d_out (floats):
//   PV_A  @0       : [bi:32][14336]   V1 o*3+h | V2 6144+o*3+w | V3 12288+o
//   PV_B  @458752  : [bo*4+wv:128][2048]  V4 partial per wave
//   PU_A  @720896  : [bo:32][30720]   U1 i*3+w | U2 6144+i*3+h | U3 12288+i*9+m
//   PU_B  @1703936 : [bi:32][18432]   U4 o*9+m
#define PVA 0
#define PVB 458752
#define PUA 720896
#define PUB 1703936

// ---- workspace layout (floats) ----
#define WS_U1 0          // 6144  u1[i*3+w]
#define WS_U2 6144       // 6144  u2[i*3+h]
#define WS_U3 12288      // 18432 u3[i*9+m]
#define WS_U4 30720      // 18432 u4[o*9+m]
#define WS_V1 49152      // 6144  v1[o*3+h]
#define WS_V2 55296      // 6144  v2[o*3+w]
#define WS_V3 61440      // 2048  v3[o]
#define WS_V4 63488      // 2048  v4[i]
#define WS_NU 65536      // 4
#define WS_NV 65540      // 4
#define WS_SIG 65544     // 1  (inv sigma)

__device__ __forceinline__ void gAtomicAdd(float* p, float v) {
    unsafeAtomicAdd(p, v);   // global_atomic_add_f32 on gfx950 (only norm scalars now)
}

__device__ __forceinline__ float wsum16(float v) {   // sum over 16 consecutive lanes
    v += __shfl_xor(v, 1);  v += __shfl_xor(v, 2);
    v += __shfl_xor(v, 4);  v += __shfl_xor(v, 8);
    return v;
}
__device__ __forceinline__ float wsum4x16(float v) { // sum over lanes {u,u+16,u+32,u+48}
    v += __shfl_xor(v, 16); v += __shfl_xor(v, 32);
    return v;
}

__device__ __forceinline__ float blockReduceSum(float v) {
    __shared__ float sh[4];
    #pragma unroll
    for (int off = 1; off < 64; off <<= 1) v += __shfl_xor(v, off);
    const int w = threadIdx.x >> 6;
    if ((threadIdx.x & 63) == 0) sh[w] = v;
    __syncthreads();
    float r = 0.f;
    if (threadIdx.x == 0) r = sh[0] + sh[1] + sh[2] + sh[3];
    return r;
}

// zero norm scalars only (partials need no pre-zero: fully overwritten)
__global__ void initZero(float* ws) {
    if (threadIdx.x < 12) ws[WS_NU + threadIdx.x] = 0.f;
}

// copy input u's into ws, accumulate squared norms into nu[4]
__global__ void initU(const float* __restrict__ u1, const float* __restrict__ u2,
                      const float* __restrict__ u3, const float* __restrict__ u4,
                      float* __restrict__ ws) {
    const int tid = blockIdx.x * 256 + threadIdx.x;   // grid 192*256 = 49152
    float val; int c;
    if (tid < 6144)       { val = u1[tid];          c = 0; }
    else if (tid < 12288) { val = u2[tid - 6144];   c = 1; }
    else if (tid < 30720) { val = u3[tid - 12288];  c = 2; }
    else                  { val = u4[tid - 30720];  c = 3; }
    ws[WS_U1 + tid] = val;
    float bs = blockReduceSum(val * val);
    if (threadIdx.x == 0) gAtomicAdd(&ws[WS_NU + c], bs);
}

#define PROC_V(off, kvv) { \
    const int iq = (off) / 9, mm = (off) % 9, hh = mm / 3, wq = mm % 3; \
    b1[hh]  += (kvv) * w1[iq * 3 + wq]; \
    b2[wq]  += (kvv) * w2[iq * 3 + hh]; \
    b3      += (kvv) * u3v[off]; \
    a4[iq]  += (kvv) * u4row[mm]; }

__global__ __launch_bounds__(256) void passV(const float4* __restrict__ K4,
                                             float* __restrict__ ws,
                                             float* __restrict__ scr) {
    const int b  = blockIdx.x;
    const int bo = b >> 5, bi = b & 31;
    const int o0 = bo * 64, i0 = bi * 64;
    const int t = threadIdx.x;
    const int u = t & 15, a = t >> 4;
    const int lane = t & 63, wv = t >> 6;

    const float inv1 = 1.f / (sqrtf(ws[WS_NU + 0]) + EPSV);
    const float inv2 = 1.f / (sqrtf(ws[WS_NU + 1]) + EPSV);
    const float inv3 = 1.f / (sqrtf(ws[WS_NU + 2]) + EPSV);
    const float inv4 = 1.f / (sqrtf(ws[WS_NU + 3]) + EPSV);

    const int ib = i0 + 4 * u;          // first i of this thread
    // thread-fixed i-side weights
    float w1[12], w2[12], u3v[36];
    {
        const float4* U1v = reinterpret_cast<const float4*>(ws + WS_U1);
        const float4* U2v = reinterpret_cast<const float4*>(ws + WS_U2);
        const float4* U3v = reinterpret_cast<const float4*>(ws + WS_U3);
        #pragma unroll
        for (int q = 0; q < 3; ++q) {
            float4 f = U1v[(ib * 3) / 4 + q];
            w1[4 * q + 0] = f.x * inv1; w1[4 * q + 1] = f.y * inv1;
            w1[4 * q + 2] = f.z * inv1; w1[4 * q + 3] = f.w * inv1;
            float4 g = U2v[(ib * 3) / 4 + q];
            w2[4 * q + 0] = g.x * inv2; w2[4 * q + 1] = g.y * inv2;
            w2[4 * q + 2] = g.z * inv2; w2[4 * q + 3] = g.w * inv2;
        }
        #pragma unroll
        for (int q = 0; q < 9; ++q) {
            float4 f = U3v[(ib * 9) / 4 + q];
            u3v[4 * q + 0] = f.x * inv3; u3v[4 * q + 1] = f.y * inv3;
            u3v[4 * q + 2] = f.z * inv3; u3v[4 * q + 3] = f.w * inv3;
        }
    }

    float a4[4] = {0.f, 0.f, 0.f, 0.f};
    for (int k = 0; k < 4; ++k) {
        const int o = o0 + a + 16 * k;
        float u4row[9];
        #pragma unroll
        for (int m = 0; m < 9; ++m) u4row[m] = ws[WS_U4 + o * 9 + m] * inv4;
        const int f4base = o * 4608 + bi * 144 + 9 * u;
        float b1[3] = {0.f, 0.f, 0.f}, b2[3] = {0.f, 0.f, 0.f}, b3 = 0.f;
        #pragma unroll
        for (int c = 0; c < 9; ++c) {
            float4 kq = K4[f4base + c];
            { const int off = 4 * c + 0; PROC_V(off, kq.x); }
            { const int off = 4 * c + 1; PROC_V(off, kq.y); }
            { const int off = 4 * c + 2; PROC_V(off, kq.z); }
            { const int off = 4 * c + 3; PROC_V(off, kq.w); }
        }
        #pragma unroll
        for (int hh = 0; hh < 3; ++hh) {
            float s = wsum16(b1[hh]);
            if (u == 0) scr[PVA + bi * 14336 + o * 3 + hh] = s;
        }
        #pragma unroll
        for (int wq = 0; wq < 3; ++wq) {
            float s = wsum16(b2[wq]);
            if (u == 0) scr[PVA + bi * 14336 + 6144 + o * 3 + wq] = s;
        }
        {
            float s = wsum16(b3);
            if (u == 0) scr[PVA + bi * 14336 + 12288 + o] = s;
        }
    }
    #pragma unroll
    for (int iq = 0; iq < 4; ++iq) {
        float s = wsum4x16(a4[iq]);
        if (lane < 16) scr[PVB + (bo * 4 + wv) * 2048 + i0 + 4 * u + iq] = s;
    }
}

// reduce V partials -> v-raws in ws; nv += sum v^2 ; zero nu
__global__ void normVzeroU(float* __restrict__ ws, const float* __restrict__ scr) {
    const int j = blockIdx.x * 256 + threadIdx.x;     // grid 64*256 = 16384
    float sum = 0.f;
    if (j < 14336) {
        #pragma unroll
        for (int s = 0; s < 32; ++s) sum += scr[PVA + s * 14336 + j];
    } else {
        const int jj = j - 14336;
        #pragma unroll 8
        for (int s = 0; s < 128; ++s) sum += scr[PVB + s * 2048 + jj];
    }
    ws[WS_V1 + j] = sum;
    const int c = (j < 6144) ? 0 : (j < 12288) ? 1 : (j < 14336) ? 2 : 3;
    float bs = blockReduceSum(sum * sum);
    if (threadIdx.x == 0) gAtomicAdd(&ws[WS_NV + c], bs);
    if (blockIdx.x == 0 && threadIdx.x < 4) ws[WS_NU + threadIdx.x] = 0.f;
}

#define PROC_U(off, kvv) { \
    const int iq = (off) / 9, mm = (off) % 9, hh = mm / 3, wq = mm % 3; \
    c1[iq * 3 + wq] += (kvv) * v1row[hh]; \
    c2[iq * 3 + hh] += (kvv) * v2row[wq]; \
    c3[off]         += (kvv) * v3v; \
    d4[mm]          += (kvv) * v4val[iq]; }

__global__ __launch_bounds__(256) void passU(const float4* __restrict__ K4,
                                             float* __restrict__ ws,
                                             float* __restrict__ scr) {
    __shared__ float red[3840];
    const int b  = blockIdx.x;
    const int bo = b >> 5, bi = b & 31;
    const int o0 = bo * 64, i0 = bi * 64;
    const int t = threadIdx.x;
    const int u = t & 15, a = t >> 4;
    const int lane = t & 63, Wv = t >> 6;

    const float iv1 = 1.f / (sqrtf(ws[WS_NV + 0]) + EPSV);
    const float iv2 = 1.f / (sqrtf(ws[WS_NV + 1]) + EPSV);
    const float iv3 = 1.f / (sqrtf(ws[WS_NV + 2]) + EPSV);
    const float iv4 = 1.f / (sqrtf(ws[WS_NV + 3]) + EPSV);

    const int ib = i0 + 4 * u;
    float v4val[4];
    {
        float4 f = *reinterpret_cast<const float4*>(ws + WS_V4 + ib);
        v4val[0] = f.x * iv4; v4val[1] = f.y * iv4;
        v4val[2] = f.z * iv4; v4val[3] = f.w * iv4;
    }

    float c1[12], c2[12], c3[36];
    #pragma unroll
    for (int v = 0; v < 12; ++v) { c1[v] = 0.f; c2[v] = 0.f; }
    #pragma unroll
    for (int v = 0; v < 36; ++v) c3[v] = 0.f;

    for (int k = 0; k < 4; ++k) {
        const int o = o0 + a + 16 * k;
        float v1row[3], v2row[3];
        #pragma unroll
        for (int hh = 0; hh < 3; ++hh) v1row[hh] = ws[WS_V1 + o * 3 + hh] * iv1;
        #pragma unroll
        for (int wq = 0; wq < 3; ++wq) v2row[wq] = ws[WS_V2 + o * 3 + wq] * iv2;
        const float v3v = ws[WS_V3 + o] * iv3;
        const int f4base = o * 4608 + bi * 144 + 9 * u;
        float d4[9];
        #pragma unroll
        for (int m = 0; m < 9; ++m) d4[m] = 0.f;
        #pragma unroll
        for (int c = 0; c < 9; ++c) {
            float4 kq = K4[f4base + c];
            { const int off = 4 * c + 0; PROC_U(off, kq.x); }
            { const int off = 4 * c + 1; PROC_U(off, kq.y); }
            { const int off = 4 * c + 2; PROC_U(off, kq.z); }
            { const int off = 4 * c + 3; PROC_U(off, kq.w); }
        }
        #pragma unroll
        for (int m = 0; m < 9; ++m) {
            float s = wsum16(d4[m]);
            if (u == 0) scr[PUB + bi * 18432 + o * 9 + m] = s;
        }
    }

    // chains 1-3: sum over this wave's 4 a-groups, then across 4 waves via LDS
    #pragma unroll
    for (int v = 0; v < 12; ++v) { c1[v] = wsum4x16(c1[v]); c2[v] = wsum4x16(c2[v]); }
    #pragma unroll
    for (int v = 0; v < 36; ++v) c3[v] = wsum4x16(c3[v]);
    if (lane < 16) {
        float* dst = &red[Wv * 960 + lane * 60];
        #pragma unroll
        for (int v = 0; v < 12; ++v) dst[v] = c1[v];
        #pragma unroll
        for (int v = 0; v < 12; ++v) dst[12 + v] = c2[v];
        #pragma unroll
        for (int v = 0; v < 36; ++v) dst[24 + v] = c3[v];
    }
    __syncthreads();
    for (int s0 = t; s0 < 960; s0 += 256) {
        float sum = red[s0] + red[960 + s0] + red[1920 + s0] + red[2880 + s0];
        const int uu = s0 / 60, v = s0 % 60;
        const int ibase = i0 + 4 * uu;
        if (v < 12) {
            scr[PUA + bo * 30720 + (ibase + v / 3) * 3 + (v % 3)] = sum;
        } else if (v < 24) {
            const int vv = v - 12;
            scr[PUA + bo * 30720 + 6144 + (ibase + vv / 3) * 3 + (vv % 3)] = sum;
        } else {
            const int vv = v - 24;
            scr[PUA + bo * 30720 + 12288 + ibase * 9 + vv] = sum;
        }
    }
}

// reduce U partials -> u-raws in ws; nu += sum u^2 ; zero nv
__global__ void normUzeroV(float* __restrict__ ws, const float* __restrict__ scr) {
    const int j = blockIdx.x * 256 + threadIdx.x;     // grid 192*256 = 49152
    float sum = 0.f;
    if (j < 30720) {
        #pragma unroll
        for (int s = 0; s < 32; ++s) sum += scr[PUA + s * 30720 + j];
    } else {
        const int jj = j - 30720;
        #pragma unroll
        for (int s = 0; s < 32; ++s) sum += scr[PUB + s * 18432 + jj];
    }
    ws[WS_U1 + j] = sum;
    const int c = (j < 6144) ? 0 : (j < 12288) ? 1 : (j < 30720) ? 2 : 3;
    float bs = blockReduceSum(sum * sum);
    if (threadIdx.x == 0) gAtomicAdd(&ws[WS_NU + c], bs);
    if (blockIdx.x == 0 && threadIdx.x < 4) ws[WS_NV + threadIdx.x] = 0.f;
}

__global__ void sigmaK(float* __restrict__ ws) {
    if (threadIdx.x == 0) {
        float smin = 1e30f;
        #pragma unroll
        for (int c = 0; c < 4; ++c) {
            float S = ws[WS_NU + c];
            float sg = S / (sqrtf(S) + EPSV);
            smin = fminf(smin, sg);
        }
        ws[WS_SIG] = 1.0f / smin;
    }
}

__global__ __launch_bounds__(256) void scaleK(const float4* __restrict__ K4,
                                              const float* __restrict__ ws,
                                              float4* __restrict__ out4) {
    const float inv = ws[WS_SIG];
    const int idx = blockIdx.x * 256 + threadIdx.x;   // grid 4608*256
    #pragma unroll
    for (int r = 0; r < 8; ++r) {
        const int j = idx + r * 1179648;
        float4 kq = K4[j];
        kq.x *= inv; kq.y *= inv; kq.z *= inv; kq.w *= inv;
        out4[j] = kq;
    }
}

extern "C" void kernel_launch(void* const* d_in, const int* in_sizes, int n_in,
                              void* d_out, int out_size, void* d_ws, size_t ws_size,
                              hipStream_t stream) {
    const float4* K4 = (const float4*)d_in[0];
    float* ws = (float*)d_ws;                 // needs 262,180 bytes
    float4* out4 = (float4*)d_out;
    float* scr = (float*)d_out;               // 9.2 MB of partials, dead until scaleK

    initZero<<<1, 64, 0, stream>>>(ws);
    initU<<<192, 256, 0, stream>>>((const float*)d_in[1], (const float*)d_in[2],
                                   (const float*)d_in[3], (const float*)d_in[4], ws);
    for (int it = 0; it < 3; ++it) {
        passV<<<1024, 256, 0, stream>>>(K4, ws, scr);
        normVzeroU<<<64, 256, 0, stream>>>(ws, scr);
        passU<<<1024, 256, 0, stream>>>(K4, ws, scr);
        normUzeroV<<<192, 256, 0, stream>>>(ws, scr);
    }
    sigmaK<<<1, 64, 0, stream>>>(ws);
    scaleK<<<4608, 256, 0, stream>>>(K4, ws, out4);
}